// Round 8
// baseline (305.579 us; speedup 1.0000x reference)
//
#include <hip/hip_runtime.h>

constexpr int NCIR = 585;
constexpr int NDIS = 88;
constexpr int NT   = NCIR + NDIS;   // 673 nodes (c: [0,585), d: [585,673))
constexpr int DIM  = 128;
constexpr int NH   = 8;
constexpr int ECC  = 20000;
constexpr int EDD  = 3000;
constexpr int ET   = ECC + EDD;     // 23000 edges
constexpr int CO   = 256;
constexpr int F1C  = (NCIR + 3) / 4;   // 147 c-blocks (4 nodes each)
constexpr int F1D  = (NDIS + 3) / 4;   // 22 d-blocks
constexpr int CH   = 64;               // att chunk (edges per LDS sweep)

struct P {
  const float *x_c, *x_d, *mat_c, *mat_d;
  const float *g1w_c, *g1b_c, *aw_c, *as_c, *ad_c, *ae_c, *we_c, *ab_c, *g2w_c, *g2b_c;
  const float *g1w_d, *g1b_d, *aw_d, *as_d, *ad_d, *ae_d, *we_d, *ab_d, *g2w_d, *g2b_d;
  const float *cw_c, *cb_c, *cw_d, *cb_d;
  const int *csrc, *cdst, *dsrc, *ddst;
  float *ew, *dinv, *easum, *wedot, *hs, *hd, *h, *f1, *hg, *fill_w;
  int *rowptr, *fill_s;
  float *out_score, *out_cir, *out_dis;
};

// ---- single-block setup: ew gather, degrees/counts (LDS), scan -> CSR,
//      dinv, per-branch mean(ew), wedot[16] ----
__global__ __launch_bounds__(1024) void k_setup(P p){
  __shared__ float wdeg_sh[NT];
  __shared__ int   cnt_sh[NT];
  __shared__ int   sd[1024];
  __shared__ float es_sh[2];
  int t = threadIdx.x;
  if (t < NT){ wdeg_sh[t] = 0.0f; cnt_sh[t] = 0; }
  if (t < 2) es_sh[t] = 0.0f;
  __syncthreads();
  float ec = 0.0f, ed = 0.0f;
  for (int e = t; e < ET; e += 1024){
    int s, d; float w;
    if (e < ECC){ s = p.csrc[e]; d = p.cdst[e]; w = p.mat_c[s * NCIR + d]; ec += w; }
    else { int el = e - ECC; s = p.dsrc[el]; d = NCIR + p.ddst[el];
           w = p.mat_d[s * NDIS + (d - NCIR)]; ed += w; }
    p.ew[e] = w;
    atomicAdd(&wdeg_sh[d], w);
    atomicAdd(&cnt_sh[d], 1);
  }
  #pragma unroll
  for (int off = 32; off; off >>= 1){
    ec += __shfl_down(ec, off, 64); ed += __shfl_down(ed, off, 64);
  }
  if ((t & 63) == 0){ atomicAdd(&es_sh[0], ec); atomicAdd(&es_sh[1], ed); }
  __syncthreads();
  int v0 = (t < NT) ? cnt_sh[t] : 0;
  sd[t] = v0;
  __syncthreads();
  for (int off = 1; off < 1024; off <<= 1){
    int v = (t >= off) ? sd[t - off] : 0;
    __syncthreads();
    sd[t] += v;
    __syncthreads();
  }
  if (t < NT){
    p.rowptr[t + 1] = sd[t];
    p.dinv[t] = rsqrtf(1.0f + wdeg_sh[t]);   // self-loop weight 1 + weighted in-deg
  }
  if (t == 0){ p.rowptr[0] = 0; p.easum[0] = es_sh[0] / (float)ECC; }
  if (t == 1){ p.easum[1] = es_sh[1] / (float)EDD; }
  { // wedot[w] = <We[h], a_edge[h]>, w = br*8+h
    int w = t >> 6, lane = t & 63, hh = w & 7;
    const float* We = (w >= 8) ? p.we_d : p.we_c;
    const float* Ae = (w >= 8) ? p.ae_d : p.ae_c;
    float v = We[hh * DIM + lane] * Ae[hh * DIM + lane]
            + We[hh * DIM + 64 + lane] * Ae[hh * DIM + 64 + lane];
    #pragma unroll
    for (int off = 32; off; off >>= 1) v += __shfl_down(v, off, 64);
    if (lane == 0) p.wedot[w] = v;
  }
  __syncthreads();
  if (t < NT) cnt_sh[t] = sd[t] - v0;       // exclusive cursor
  __syncthreads();
  for (int e = t; e < ET; e += 1024){
    int s, d;
    if (e < ECC){ s = p.csrc[e]; d = p.cdst[e]; }
    else { int el = e - ECC; s = NCIR + p.dsrc[el]; d = NCIR + p.ddst[el]; }
    int pos = atomicAdd(&cnt_sh[d], 1);
    p.fill_s[pos] = s;
    p.fill_w[pos] = p.ew[e];
  }
}

// ---- GCN1 dense: h[u] = x[u] @ W1 ----
__global__ void k_gemm128(P p){
  __shared__ float a_sh[DIM];
  int u = blockIdx.x, t = threadIdx.x;      // 128 threads
  int br = u >= NCIR;
  a_sh[t] = br ? p.x_d[(u - NCIR) * DIM + t] : p.x_c[u * DIM + t];
  __syncthreads();
  const float* W = br ? p.g1w_d : p.g1w_c;
  float acc = 0.0f;
  #pragma unroll 8
  for (int c = 0; c < DIM; ++c) acc += a_sh[c] * W[c * DIM + t];
  p.h[u * DIM + t] = acc;
}

// ---- fuse1: GCN1 agg -> f1 -> relu -> GAT proj (hg) -> attention dots ----
__global__ __launch_bounds__(256) void k_fuse1(P p){
  __shared__ float a_sh[4][DIM];
  int b = blockIdx.x, t = threadIdx.x;      // 256 threads, 4 nodes
  int base, count, br;
  if (b < F1C){ base = b * 4; count = min(4, NCIR - base); br = 0; }
  else { base = NCIR + (b - F1C) * 4; count = 4; br = 1; }
  const float* B1 = br ? p.g1b_d : p.g1b_c;
  int n2 = t >> 7, k = t & 127;
  for (int r = 0; r < 2; ++r){
    int nn = n2 + r * 2;
    float v = 0.0f;
    if (nn < count){
      int u = base + nn;
      float dv = p.dinv[u];
      float acc = B1[k] + p.h[u * DIM + k] * dv * dv;
      int beg = p.rowptr[u], end = p.rowptr[u + 1];
      for (int j = beg; j < end; ++j){
        int s = p.fill_s[j];
        acc += p.h[s * DIM + k] * (p.dinv[s] * p.fill_w[j] * dv);
      }
      p.f1[u * DIM + k] = acc;
      v = fmaxf(acc, 0.0f);
    }
    a_sh[nn][k] = v;
  }
  __syncthreads();
  const float4* Wv = (const float4*)(br ? p.aw_d : p.aw_c);  // row = 256 float4
  float4 acc4[4];
  #pragma unroll
  for (int n = 0; n < 4; ++n) acc4[n] = make_float4(0.f, 0.f, 0.f, 0.f);
  #pragma unroll 2
  for (int c = 0; c < DIM; ++c){
    float4 w = Wv[c * 256 + t];
    #pragma unroll
    for (int n = 0; n < 4; ++n){
      float a = a_sh[n][c];
      acc4[n].x += a * w.x; acc4[n].y += a * w.y;
      acc4[n].z += a * w.z; acc4[n].w += a * w.w;
    }
  }
  for (int n = 0; n < count; ++n)
    *(float4*)(p.hg + (size_t)(base + n) * 1024 + t * 4) = acc4[n];
  // dots straight from accumulator registers: thread t holds cols t*4..t*4+3
  const float* As = br ? p.as_d : p.as_c;
  const float* Ad = br ? p.ad_d : p.ad_c;
  int hh = t >> 5, kb = (t & 31) * 4;       // head, col-within-head
  #pragma unroll
  for (int n = 0; n < 4; ++n){
    float sdot = 0.0f, ddot = 0.0f;
    const float* A4 = (const float*)&acc4[n];
    #pragma unroll
    for (int q = 0; q < 4; ++q){
      sdot += A4[q] * As[hh * DIM + kb + q];
      ddot += A4[q] * Ad[hh * DIM + kb + q];
    }
    #pragma unroll
    for (int off = 16; off; off >>= 1){     // reduce 32-lane head group
      sdot += __shfl_down(sdot, off, 64);
      ddot += __shfl_down(ddot, off, 64);
    }
    if ((t & 31) == 0 && n < count){
      p.hs[(base + n) * NH + hh] = sdot;
      p.hd[(base + n) * NH + hh] = ddot;
    }
  }
}

// ---- att: softmax-agg per dst (alphas via LDS, chunked) + fused GCN2 dense.
// (segment-max shift skipped: logits O(1), exp cannot overflow; softmax is
//  shift-invariant so the result is identical.) ----
__global__ __launch_bounds__(128) void k_att(P p){
  __shared__ float den_sh[NH], hd_sh[NH], inv_sh[NH], wself_sh[NH];
  __shared__ float alpha_sh[CH * NH];
  __shared__ int   s_sh[CH];
  __shared__ float a_sh[DIM];
  int d = blockIdx.x, t = threadIdx.x;      // 128 threads
  int br = d >= NCIR;
  const float* wd = p.wedot + br * NH;
  if (t < NH){ den_sh[t] = 0.0f; hd_sh[t] = p.hd[d * NH + t]; }
  __syncthreads();
  int beg = p.rowptr[d], end = p.rowptr[d + 1];
  int deg = end - beg;
  float slw = p.easum[br];                  // self-loop edge weight = mean(ew)
  for (int idx = t; idx < deg * NH; idx += 128){
    int j = beg + (idx >> 3), hh = idx & 7;
    int s = p.fill_s[j];
    float a = p.hs[s * NH + hh] + hd_sh[hh] + p.fill_w[j] * wd[hh];
    a = a > 0.0f ? a : 0.2f * a;
    atomicAdd(&den_sh[hh], expf(a));
  }
  __syncthreads();
  if (t < NH){
    float a = p.hs[d * NH + t] + hd_sh[t] + slw * wd[t];
    a = a > 0.0f ? a : 0.2f * a;
    float ex = expf(a);
    float inv = 1.0f / (den_sh[t] + ex + 1e-16f) * 0.125f;  // /(den+eps)/H
    inv_sh[t] = inv;
    wself_sh[t] = ex * inv;
  }
  __syncthreads();
  float acc = (br ? p.ab_d : p.ab_c)[t];
  {
    const float* r = p.hg + (size_t)d * 1024;
    #pragma unroll
    for (int hh = 0; hh < NH; ++hh) acc += wself_sh[hh] * r[hh * DIM + t];
  }
  for (int j0 = beg; j0 < end; j0 += CH){
    int m = min(CH, end - j0);
    for (int idx = t; idx < m * NH; idx += 128){
      int jj = idx >> 3, hh = idx & 7;
      int j = j0 + jj;
      int s = p.fill_s[j];
      float a = p.hs[s * NH + hh] + hd_sh[hh] + p.fill_w[j] * wd[hh];
      a = a > 0.0f ? a : 0.2f * a;
      alpha_sh[idx] = expf(a) * inv_sh[hh];
    }
    if (t < m) s_sh[t] = p.fill_s[j0 + t];
    __syncthreads();
    for (int jj = 0; jj < m; ++jj){
      const float* r = p.hg + (size_t)s_sh[jj] * 1024;
      #pragma unroll
      for (int hh = 0; hh < NH; ++hh) acc += alpha_sh[jj * NH + hh] * r[hh * DIM + t];
    }
    __syncthreads();
  }
  // fused GCN2 dense: h2[d] = relu(att[d]) @ W2 (att never leaves the block)
  a_sh[t] = fmaxf(acc, 0.0f);
  __syncthreads();
  const float* W = br ? p.g2w_d : p.g2w_c;
  float h2 = 0.0f;
  #pragma unroll 8
  for (int c = 0; c < DIM; ++c) h2 += a_sh[c] * W[c * DIM + t];
  p.h[d * DIM + t] = h2;
}

// ---- fuse2: GCN2 agg -> f2 -> CNN head (f2 never leaves the block) ----
__global__ __launch_bounds__(256) void k_fuse2(P p){
  __shared__ float s12[4][2 * DIM];
  int b = blockIdx.x, o = threadIdx.x;      // 256 threads, 4 nodes
  int gbase, count, br; float* out;
  if (b < F1C){ gbase = b * 4; count = min(4, NCIR - gbase); br = 0;
                out = p.out_cir + (size_t)gbase * CO; }
  else { int lb = (b - F1C) * 4; gbase = NCIR + lb; count = 4; br = 1;
         out = p.out_dis + (size_t)lb * CO; }
  const float* B2 = br ? p.g2b_d : p.g2b_c;
  int n2 = o >> 7, k = o & 127;
  for (int r = 0; r < 2; ++r){
    int nn = n2 + r * 2;
    float v1 = 0.0f, v2 = 0.0f;
    if (nn < count){
      int u = gbase + nn;
      float dv = p.dinv[u];
      float acc = B2[k] + p.h[u * DIM + k] * dv * dv;
      int beg = p.rowptr[u], end = p.rowptr[u + 1];
      for (int j = beg; j < end; ++j){
        int s = p.fill_s[j];
        acc += p.h[s * DIM + k] * (p.dinv[s] * p.fill_w[j] * dv);
      }
      v2 = fmaxf(acc, 0.0f);
      v1 = fmaxf(p.f1[u * DIM + k], 0.0f);
    }
    s12[nn][k] = v1;
    s12[nn][DIM + k] = v2;
  }
  __syncthreads();
  const float* W = (br ? p.cw_d : p.cw_c) + o * 2 * DIM;
  float bv = (br ? p.cb_d : p.cb_c)[o];
  float a0 = bv, a1 = bv, a2 = bv, a3 = bv;
  #pragma unroll 4
  for (int q = 0; q < 2 * DIM; ++q){
    float wv = W[q];
    a0 += s12[0][q] * wv; a1 += s12[1][q] * wv;
    a2 += s12[2][q] * wv; a3 += s12[3][q] * wv;
  }
  if (0 < count) out[0 * CO + o] = a0;
  if (1 < count) out[1 * CO + o] = a1;
  if (2 < count) out[2 * CO + o] = a2;
  if (3 < count) out[3 * CO + o] = a3;
}

// ---- score[i,j] = <cir[i,:], dis[j,:]> ----
__global__ void k_final(P p){
  __shared__ float ci[CO];
  int i = blockIdx.x, j = threadIdx.x;      // 128 threads, 88 active
  ci[j]       = p.out_cir[i * CO + j];
  ci[DIM + j] = p.out_cir[i * CO + DIM + j];
  __syncthreads();
  if (j < NDIS){
    const float* dr = p.out_dis + j * CO;
    float acc = 0.0f;
    #pragma unroll 8
    for (int q = 0; q < CO; ++q) acc += ci[q] * dr[q];
    p.out_score[i * NDIS + j] = acc;
  }
}

extern "C" void kernel_launch(void* const* d_in, const int* in_sizes, int n_in,
                              void* d_out, int out_size, void* d_ws, size_t ws_size,
                              hipStream_t stream){
  P p;
  typedef const float* F;
  p.x_c   = (F)d_in[0];  p.x_d   = (F)d_in[1];
  p.mat_c = (F)d_in[2];  p.mat_d = (F)d_in[3];
  p.g1w_c = (F)d_in[4];  p.g1b_c = (F)d_in[5];
  p.aw_c  = (F)d_in[6];  p.as_c  = (F)d_in[7];  p.ad_c = (F)d_in[8];
  p.ae_c  = (F)d_in[9];  p.we_c  = (F)d_in[10]; p.ab_c = (F)d_in[11];
  p.g2w_c = (F)d_in[12]; p.g2b_c = (F)d_in[13];
  p.g1w_d = (F)d_in[14]; p.g1b_d = (F)d_in[15];
  p.aw_d  = (F)d_in[16]; p.as_d  = (F)d_in[17]; p.ad_d = (F)d_in[18];
  p.ae_d  = (F)d_in[19]; p.we_d  = (F)d_in[20]; p.ab_d = (F)d_in[21];
  p.g2w_d = (F)d_in[22]; p.g2b_d = (F)d_in[23];
  p.cw_c  = (F)d_in[24]; p.cb_c  = (F)d_in[25];
  p.cw_d  = (F)d_in[26]; p.cb_d  = (F)d_in[27];
  const int* cc_edges = (const int*)d_in[28];
  const int* dd_edges = (const int*)d_in[29];
  p.csrc = cc_edges;  p.cdst = cc_edges + ECC;
  p.dsrc = dd_edges;  p.ddst = dd_edges + EDD;

  float* out = (float*)d_out;
  p.out_score = out;                        // [585, 88]
  p.out_cir   = out + NCIR * NDIS;          // [585, 256]
  p.out_dis   = p.out_cir + NCIR * CO;      // [88, 256]

  float* w = (float*)d_ws;                  // ~3.8 MB of 256 MB; 16B-aligned blocks
  auto alloc = [&](size_t n){ float* q = w; w += n; return q; };
  p.ew     = alloc(ET);                     // 23000 (%4==0)
  p.dinv   = alloc(676);
  p.easum  = alloc(4);
  p.wedot  = alloc(16);
  p.hs     = alloc((size_t)NT * NH);        // 5384 (%4==0)
  p.hd     = alloc((size_t)NT * NH);
  p.h      = alloc((size_t)NT * DIM);
  p.f1     = alloc((size_t)NT * DIM);
  p.hg     = alloc((size_t)NT * 1024);
  p.fill_w = alloc(ET);
  p.rowptr = (int*)alloc(680);
  p.fill_s = (int*)alloc(ET);

  k_setup  <<<1,           1024, 0, stream>>>(p);
  k_gemm128<<<NT,          DIM,  0, stream>>>(p);
  k_fuse1  <<<F1C + F1D,   256,  0, stream>>>(p);
  k_att    <<<NT,          DIM,  0, stream>>>(p);
  k_fuse2  <<<F1C + F1D,   256,  0, stream>>>(p);
  k_final  <<<NCIR,        DIM,  0, stream>>>(p);
}

// Round 9
// 300.195 us; speedup vs baseline: 1.0179x; 1.0179x over previous
//
#include <hip/hip_runtime.h>

constexpr int NCIR = 585;
constexpr int NDIS = 88;
constexpr int NT   = NCIR + NDIS;   // 673 nodes (c: [0,585), d: [585,673))
constexpr int DIM  = 128;
constexpr int NH   = 8;
constexpr int ECC  = 20000;
constexpr int EDD  = 3000;
constexpr int ET   = ECC + EDD;     // 23000 edges
constexpr int CO   = 256;
constexpr int F1C  = (NCIR + 3) / 4;   // 147 c-blocks (4 nodes each)
constexpr int F1D  = (NDIS + 3) / 4;   // 22 d-blocks
constexpr int CH   = 64;               // att chunk (edges per LDS sweep)
constexpr int GBK  = (ET + 255) / 256; // 90 gather blocks

struct P {
  const float *x_c, *x_d, *mat_c, *mat_d;
  const float *g1w_c, *g1b_c, *aw_c, *as_c, *ad_c, *ae_c, *we_c, *ab_c, *g2w_c, *g2b_c;
  const float *g1w_d, *g1b_d, *aw_d, *as_d, *ad_d, *ae_d, *we_d, *ab_d, *g2w_d, *g2b_d;
  const float *cw_c, *cb_c, *cw_d, *cb_d;
  const int *csrc, *cdst, *dsrc, *ddst;
  float *ew, *dinv, *easum, *wedot, *hs, *hd, *h, *f1, *hg, *fill_w, *psc, *psd;
  int *rowptr, *fill_s;
  float *out_score, *out_cir, *out_dis;
};

// ---- multi-block edge-weight gather (latency-bound random mat reads need
//      whole-GPU MLP — single-block version measured 90 µs, R8).
//      Per-block partial sums -> distinct slots (no init, no atomics). ----
__global__ __launch_bounds__(256) void k_gather(P p){
  __shared__ float rc[256], rd[256];
  int t = threadIdx.x, e = blockIdx.x * 256 + t;
  float wc = 0.0f, wdv = 0.0f;
  if (e < ET){
    float w;
    if (e < ECC){
      int s = p.csrc[e], d = p.cdst[e];
      w = p.mat_c[s * NCIR + d]; wc = w;
    } else {
      int el = e - ECC;
      int s = p.dsrc[el], d = p.ddst[el];
      w = p.mat_d[s * NDIS + d]; wdv = w;
    }
    p.ew[e] = w;
  }
  rc[t] = wc; rd[t] = wdv;
  __syncthreads();
  for (int st = 128; st; st >>= 1){
    if (t < st){ rc[t] += rc[t + st]; rd[t] += rd[t + st]; }
    __syncthreads();
  }
  if (t == 0){ p.psc[blockIdx.x] = rc[0]; p.psd[blockIdx.x] = rd[0]; }
}

// ---- single-block: degree histogram (coalesced dst+ew reads), scan -> CSR
//      rowptr, dinv, easum means, wedot, CSR fill (scattered writes) ----
__global__ __launch_bounds__(1024) void k_scan(P p){
  __shared__ float wdeg_sh[NT];
  __shared__ int   cnt_sh[NT];
  __shared__ int   sd[1024];
  int t = threadIdx.x;
  if (t < NT){ wdeg_sh[t] = 0.0f; cnt_sh[t] = 0; }
  __syncthreads();
  for (int e = t; e < ET; e += 1024){
    int d = (e < ECC) ? p.cdst[e] : NCIR + p.ddst[e - ECC];
    atomicAdd(&wdeg_sh[d], p.ew[e]);
    atomicAdd(&cnt_sh[d], 1);
  }
  __syncthreads();
  int v0 = (t < NT) ? cnt_sh[t] : 0;
  sd[t] = v0;
  __syncthreads();
  for (int off = 1; off < 1024; off <<= 1){
    int v = (t >= off) ? sd[t - off] : 0;
    __syncthreads();
    sd[t] += v;
    __syncthreads();
  }
  if (t < NT){
    p.rowptr[t + 1] = sd[t];
    p.dinv[t] = rsqrtf(1.0f + wdeg_sh[t]);  // self-loop weight 1 + weighted in-deg
  }
  if (t == 0) p.rowptr[0] = 0;
  { // easum means from per-block partials (waves 0,1)
    int wv = t >> 6, lane = t & 63;
    if (wv < 2){
      const float* ps = wv ? p.psd : p.psc;
      float v = ps[lane] + (lane + 64 < GBK ? ps[lane + 64] : 0.0f);
      #pragma unroll
      for (int off = 32; off; off >>= 1) v += __shfl_down(v, off, 64);
      if (lane == 0) p.easum[wv] = v / (wv ? (float)EDD : (float)ECC);
    }
    // wedot[w] = <We[h], a_edge[h]>, w = br*8+h (all 16 waves)
    int w = t >> 6, hh = w & 7;
    const float* We = (w >= 8) ? p.we_d : p.we_c;
    const float* Ae = (w >= 8) ? p.ae_d : p.ae_c;
    float v = We[hh * DIM + lane] * Ae[hh * DIM + lane]
            + We[hh * DIM + 64 + lane] * Ae[hh * DIM + 64 + lane];
    #pragma unroll
    for (int off = 32; off; off >>= 1) v += __shfl_down(v, off, 64);
    if (lane == 0) p.wedot[w] = v;
  }
  __syncthreads();
  if (t < NT) cnt_sh[t] = sd[t] - v0;       // exclusive cursor
  __syncthreads();
  for (int e = t; e < ET; e += 1024){
    int s, d;
    if (e < ECC){ s = p.csrc[e]; d = p.cdst[e]; }
    else { int el = e - ECC; s = NCIR + p.dsrc[el]; d = NCIR + p.ddst[el]; }
    int pos = atomicAdd(&cnt_sh[d], 1);
    p.fill_s[pos] = s;
    p.fill_w[pos] = p.ew[e];
  }
}

// ---- GCN1 dense: h[u] = x[u] @ W1 ----
__global__ void k_gemm128(P p){
  __shared__ float a_sh[DIM];
  int u = blockIdx.x, t = threadIdx.x;      // 128 threads
  int br = u >= NCIR;
  a_sh[t] = br ? p.x_d[(u - NCIR) * DIM + t] : p.x_c[u * DIM + t];
  __syncthreads();
  const float* W = br ? p.g1w_d : p.g1w_c;
  float acc = 0.0f;
  #pragma unroll 8
  for (int c = 0; c < DIM; ++c) acc += a_sh[c] * W[c * DIM + t];
  p.h[u * DIM + t] = acc;
}

// ---- fuse1: GCN1 agg -> f1 -> relu -> GAT proj (hg) -> attention dots ----
__global__ __launch_bounds__(256) void k_fuse1(P p){
  __shared__ float a_sh[4][DIM];
  int b = blockIdx.x, t = threadIdx.x;      // 256 threads, 4 nodes
  int base, count, br;
  if (b < F1C){ base = b * 4; count = min(4, NCIR - base); br = 0; }
  else { base = NCIR + (b - F1C) * 4; count = 4; br = 1; }
  const float* B1 = br ? p.g1b_d : p.g1b_c;
  int n2 = t >> 7, k = t & 127;
  for (int r = 0; r < 2; ++r){
    int nn = n2 + r * 2;
    float v = 0.0f;
    if (nn < count){
      int u = base + nn;
      float dv = p.dinv[u];
      float acc = B1[k] + p.h[u * DIM + k] * dv * dv;
      int beg = p.rowptr[u], end = p.rowptr[u + 1];
      for (int j = beg; j < end; ++j){
        int s = p.fill_s[j];
        acc += p.h[s * DIM + k] * (p.dinv[s] * p.fill_w[j] * dv);
      }
      p.f1[u * DIM + k] = acc;
      v = fmaxf(acc, 0.0f);
    }
    a_sh[nn][k] = v;
  }
  __syncthreads();
  const float4* Wv = (const float4*)(br ? p.aw_d : p.aw_c);  // row = 256 float4
  float4 acc4[4];
  #pragma unroll
  for (int n = 0; n < 4; ++n) acc4[n] = make_float4(0.f, 0.f, 0.f, 0.f);
  #pragma unroll 2
  for (int c = 0; c < DIM; ++c){
    float4 w = Wv[c * 256 + t];
    #pragma unroll
    for (int n = 0; n < 4; ++n){
      float a = a_sh[n][c];
      acc4[n].x += a * w.x; acc4[n].y += a * w.y;
      acc4[n].z += a * w.z; acc4[n].w += a * w.w;
    }
  }
  for (int n = 0; n < count; ++n)
    *(float4*)(p.hg + (size_t)(base + n) * 1024 + t * 4) = acc4[n];
  // dots straight from accumulator registers: thread t holds cols t*4..t*4+3
  const float* As = br ? p.as_d : p.as_c;
  const float* Ad = br ? p.ad_d : p.ad_c;
  int hh = t >> 5, kb = (t & 31) * 4;       // head, col-within-head
  #pragma unroll
  for (int n = 0; n < 4; ++n){
    float sdot = 0.0f, ddot = 0.0f;
    const float* A4 = (const float*)&acc4[n];
    #pragma unroll
    for (int q = 0; q < 4; ++q){
      sdot += A4[q] * As[hh * DIM + kb + q];
      ddot += A4[q] * Ad[hh * DIM + kb + q];
    }
    #pragma unroll
    for (int off = 16; off; off >>= 1){     // reduce 32-lane head group
      sdot += __shfl_down(sdot, off, 64);
      ddot += __shfl_down(ddot, off, 64);
    }
    if ((t & 31) == 0 && n < count){
      p.hs[(base + n) * NH + hh] = sdot;
      p.hd[(base + n) * NH + hh] = ddot;
    }
  }
}

// ---- att: softmax-agg per dst (alphas via LDS, chunked) + fused GCN2 dense.
// (segment-max shift skipped: logits O(1), exp cannot overflow; softmax is
//  shift-invariant so the result is identical.) ----
__global__ __launch_bounds__(128) void k_att(P p){
  __shared__ float den_sh[NH], hd_sh[NH], inv_sh[NH], wself_sh[NH];
  __shared__ float alpha_sh[CH * NH];
  __shared__ int   s_sh[CH];
  __shared__ float a_sh[DIM];
  int d = blockIdx.x, t = threadIdx.x;      // 128 threads
  int br = d >= NCIR;
  const float* wd = p.wedot + br * NH;
  if (t < NH){ den_sh[t] = 0.0f; hd_sh[t] = p.hd[d * NH + t]; }
  __syncthreads();
  int beg = p.rowptr[d], end = p.rowptr[d + 1];
  int deg = end - beg;
  float slw = p.easum[br];                  // self-loop edge weight = mean(ew)
  for (int idx = t; idx < deg * NH; idx += 128){
    int j = beg + (idx >> 3), hh = idx & 7;
    int s = p.fill_s[j];
    float a = p.hs[s * NH + hh] + hd_sh[hh] + p.fill_w[j] * wd[hh];
    a = a > 0.0f ? a : 0.2f * a;
    atomicAdd(&den_sh[hh], expf(a));
  }
  __syncthreads();
  if (t < NH){
    float a = p.hs[d * NH + t] + hd_sh[t] + slw * wd[t];
    a = a > 0.0f ? a : 0.2f * a;
    float ex = expf(a);
    float inv = 1.0f / (den_sh[t] + ex + 1e-16f) * 0.125f;  // /(den+eps)/H
    inv_sh[t] = inv;
    wself_sh[t] = ex * inv;
  }
  __syncthreads();
  float acc = (br ? p.ab_d : p.ab_c)[t];
  {
    const float* r = p.hg + (size_t)d * 1024;
    #pragma unroll
    for (int hh = 0; hh < NH; ++hh) acc += wself_sh[hh] * r[hh * DIM + t];
  }
  for (int j0 = beg; j0 < end; j0 += CH){
    int m = min(CH, end - j0);
    for (int idx = t; idx < m * NH; idx += 128){
      int jj = idx >> 3, hh = idx & 7;
      int j = j0 + jj;
      int s = p.fill_s[j];
      float a = p.hs[s * NH + hh] + hd_sh[hh] + p.fill_w[j] * wd[hh];
      a = a > 0.0f ? a : 0.2f * a;
      alpha_sh[idx] = expf(a) * inv_sh[hh];
    }
    if (t < m) s_sh[t] = p.fill_s[j0 + t];
    __syncthreads();
    for (int jj = 0; jj < m; ++jj){
      const float* r = p.hg + (size_t)s_sh[jj] * 1024;
      #pragma unroll
      for (int hh = 0; hh < NH; ++hh) acc += alpha_sh[jj * NH + hh] * r[hh * DIM + t];
    }
    __syncthreads();
  }
  // fused GCN2 dense: h2[d] = relu(att[d]) @ W2 (att never leaves the block)
  a_sh[t] = fmaxf(acc, 0.0f);
  __syncthreads();
  const float* W = br ? p.g2w_d : p.g2w_c;
  float h2 = 0.0f;
  #pragma unroll 8
  for (int c = 0; c < DIM; ++c) h2 += a_sh[c] * W[c * DIM + t];
  p.h[d * DIM + t] = h2;
}

// ---- fuse2: GCN2 agg -> f2 -> CNN head (f2 never leaves the block) ----
__global__ __launch_bounds__(256) void k_fuse2(P p){
  __shared__ float s12[4][2 * DIM];
  int b = blockIdx.x, o = threadIdx.x;      // 256 threads, 4 nodes
  int gbase, count, br; float* out;
  if (b < F1C){ gbase = b * 4; count = min(4, NCIR - gbase); br = 0;
                out = p.out_cir + (size_t)gbase * CO; }
  else { int lb = (b - F1C) * 4; gbase = NCIR + lb; count = 4; br = 1;
         out = p.out_dis + (size_t)lb * CO; }
  const float* B2 = br ? p.g2b_d : p.g2b_c;
  int n2 = o >> 7, k = o & 127;
  for (int r = 0; r < 2; ++r){
    int nn = n2 + r * 2;
    float v1 = 0.0f, v2 = 0.0f;
    if (nn < count){
      int u = gbase + nn;
      float dv = p.dinv[u];
      float acc = B2[k] + p.h[u * DIM + k] * dv * dv;
      int beg = p.rowptr[u], end = p.rowptr[u + 1];
      for (int j = beg; j < end; ++j){
        int s = p.fill_s[j];
        acc += p.h[s * DIM + k] * (p.dinv[s] * p.fill_w[j] * dv);
      }
      v2 = fmaxf(acc, 0.0f);
      v1 = fmaxf(p.f1[u * DIM + k], 0.0f);
    }
    s12[nn][k] = v1;
    s12[nn][DIM + k] = v2;
  }
  __syncthreads();
  const float* W = (br ? p.cw_d : p.cw_c) + o * 2 * DIM;
  float bv = (br ? p.cb_d : p.cb_c)[o];
  float a0 = bv, a1 = bv, a2 = bv, a3 = bv;
  #pragma unroll 4
  for (int q = 0; q < 2 * DIM; ++q){
    float wv = W[q];
    a0 += s12[0][q] * wv; a1 += s12[1][q] * wv;
    a2 += s12[2][q] * wv; a3 += s12[3][q] * wv;
  }
  if (0 < count) out[0 * CO + o] = a0;
  if (1 < count) out[1 * CO + o] = a1;
  if (2 < count) out[2 * CO + o] = a2;
  if (3 < count) out[3 * CO + o] = a3;
}

// ---- score[i,j] = <cir[i,:], dis[j,:]> ----
__global__ void k_final(P p){
  __shared__ float ci[CO];
  int i = blockIdx.x, j = threadIdx.x;      // 128 threads, 88 active
  ci[j]       = p.out_cir[i * CO + j];
  ci[DIM + j] = p.out_cir[i * CO + DIM + j];
  __syncthreads();
  if (j < NDIS){
    const float* dr = p.out_dis + j * CO;
    float acc = 0.0f;
    #pragma unroll 8
    for (int q = 0; q < CO; ++q) acc += ci[q] * dr[q];
    p.out_score[i * NDIS + j] = acc;
  }
}

extern "C" void kernel_launch(void* const* d_in, const int* in_sizes, int n_in,
                              void* d_out, int out_size, void* d_ws, size_t ws_size,
                              hipStream_t stream){
  P p;
  typedef const float* F;
  p.x_c   = (F)d_in[0];  p.x_d   = (F)d_in[1];
  p.mat_c = (F)d_in[2];  p.mat_d = (F)d_in[3];
  p.g1w_c = (F)d_in[4];  p.g1b_c = (F)d_in[5];
  p.aw_c  = (F)d_in[6];  p.as_c  = (F)d_in[7];  p.ad_c = (F)d_in[8];
  p.ae_c  = (F)d_in[9];  p.we_c  = (F)d_in[10]; p.ab_c = (F)d_in[11];
  p.g2w_c = (F)d_in[12]; p.g2b_c = (F)d_in[13];
  p.g1w_d = (F)d_in[14]; p.g1b_d = (F)d_in[15];
  p.aw_d  = (F)d_in[16]; p.as_d  = (F)d_in[17]; p.ad_d = (F)d_in[18];
  p.ae_d  = (F)d_in[19]; p.we_d  = (F)d_in[20]; p.ab_d = (F)d_in[21];
  p.g2w_d = (F)d_in[22]; p.g2b_d = (F)d_in[23];
  p.cw_c  = (F)d_in[24]; p.cb_c  = (F)d_in[25];
  p.cw_d  = (F)d_in[26]; p.cb_d  = (F)d_in[27];
  const int* cc_edges = (const int*)d_in[28];
  const int* dd_edges = (const int*)d_in[29];
  p.csrc = cc_edges;  p.cdst = cc_edges + ECC;
  p.dsrc = dd_edges;  p.ddst = dd_edges + EDD;

  float* out = (float*)d_out;
  p.out_score = out;                        // [585, 88]
  p.out_cir   = out + NCIR * NDIS;          // [585, 256]
  p.out_dis   = p.out_cir + NCIR * CO;      // [88, 256]

  float* w = (float*)d_ws;                  // ~3.8 MB of 256 MB; 16B-aligned blocks
  auto alloc = [&](size_t n){ float* q = w; w += n; return q; };
  p.ew     = alloc(ET);                     // 23000 (%4==0)
  p.dinv   = alloc(676);
  p.easum  = alloc(4);
  p.wedot  = alloc(16);
  p.psc    = alloc(92);
  p.psd    = alloc(92);
  p.hs     = alloc((size_t)NT * NH);        // 5384 (%4==0)
  p.hd     = alloc((size_t)NT * NH);
  p.h      = alloc((size_t)NT * DIM);
  p.f1     = alloc((size_t)NT * DIM);
  p.hg     = alloc((size_t)NT * 1024);
  p.fill_w = alloc(ET);
  p.rowptr = (int*)alloc(680);
  p.fill_s = (int*)alloc(ET);

  k_gather <<<GBK,         256,  0, stream>>>(p);
  k_scan   <<<1,           1024, 0, stream>>>(p);
  k_gemm128<<<NT,          DIM,  0, stream>>>(p);
  k_fuse1  <<<F1C + F1D,   256,  0, stream>>>(p);
  k_att    <<<NT,          DIM,  0, stream>>>(p);
  k_fuse2  <<<F1C + F1D,   256,  0, stream>>>(p);
  k_final  <<<NCIR,        DIM,  0, stream>>>(p);
}

// Round 10
// 252.070 us; speedup vs baseline: 1.2123x; 1.1909x over previous
//
#include <hip/hip_runtime.h>

constexpr int NCIR = 585;
constexpr int NDIS = 88;
constexpr int NT   = NCIR + NDIS;   // 673 nodes (c: [0,585), d: [585,673))
constexpr int DIM  = 128;
constexpr int NH   = 8;
constexpr int ECC  = 20000;
constexpr int EDD  = 3000;
constexpr int ET   = ECC + EDD;     // 23000 edges
constexpr int CO   = 256;
constexpr int F1C  = (NCIR + 3) / 4;   // 147 c-blocks (4 nodes each)
constexpr int F1D  = (NDIS + 3) / 4;   // 22 d-blocks
constexpr int CH   = 64;               // att chunk (edges per LDS sweep)
constexpr int GBK  = (ET + 255) / 256; // 90 gather blocks

struct P {
  const float *x_c, *x_d, *mat_c, *mat_d;
  const float *g1w_c, *g1b_c, *aw_c, *as_c, *ad_c, *ae_c, *we_c, *ab_c, *g2w_c, *g2b_c;
  const float *g1w_d, *g1b_d, *aw_d, *as_d, *ad_d, *ae_d, *we_d, *ab_d, *g2w_d, *g2b_d;
  const float *cw_c, *cb_c, *cw_d, *cb_d;
  const int *csrc, *cdst, *dsrc, *ddst;
  float *ew, *dinv, *easum, *wedot, *hs, *hd, *h, *f1, *hg, *fill_w, *psc, *psd, *wdeg;
  int *cnt, *cursor, *rowptr, *fill_s;
  float *out_score, *out_cir, *out_dis;
};

// ---- multi-block gather: random mat reads (whole-GPU MLP) + GLOBAL atomic
//      degree/count histograms (90 blocks through L2 — the single-block LDS
//      version serialized 46k same-address atomics: 75 µs, R9). ----
__global__ __launch_bounds__(256) void k_gather(P p){
  __shared__ float rc[256], rd[256];
  int t = threadIdx.x, e = blockIdx.x * 256 + t;
  float wc = 0.0f, wdv = 0.0f;
  if (e < ET){
    float w; int d;
    if (e < ECC){
      int s = p.csrc[e]; d = p.cdst[e];
      w = p.mat_c[s * NCIR + d]; wc = w;
    } else {
      int el = e - ECC;
      int s = p.dsrc[el]; d = NCIR + p.ddst[el];
      w = p.mat_d[s * NDIS + (d - NCIR)]; wdv = w;
    }
    p.ew[e] = w;
    atomicAdd(&p.wdeg[d], w);
    atomicAdd(&p.cnt[d], 1);
  }
  rc[t] = wc; rd[t] = wdv;
  __syncthreads();
  for (int st = 128; st; st >>= 1){
    if (t < st){ rc[t] += rc[t + st]; rd[t] += rd[t + st]; }
    __syncthreads();
  }
  if (t == 0){ p.psc[blockIdx.x] = rc[0]; p.psd[blockIdx.x] = rd[0]; }
}

// ---- single-block, serial-only work: 673-wide scan -> rowptr/cursor,
//      dinv, easum means, wedot[16]. No 23k-element loops here. ----
__global__ __launch_bounds__(1024) void k_scan(P p){
  __shared__ int sd[1024];
  int t = threadIdx.x;
  int v0 = (t < NT) ? p.cnt[t] : 0;
  sd[t] = v0;
  __syncthreads();
  for (int off = 1; off < 1024; off <<= 1){
    int v = (t >= off) ? sd[t - off] : 0;
    __syncthreads();
    sd[t] += v;
    __syncthreads();
  }
  if (t < NT){
    p.rowptr[t + 1] = sd[t];
    p.cursor[t]     = sd[t] - v0;           // exclusive scan
    p.dinv[t] = rsqrtf(1.0f + p.wdeg[t]);   // self-loop 1 + weighted in-deg
  }
  if (t == 0) p.rowptr[0] = 0;
  int wv = t >> 6, lane = t & 63;
  if (wv < 2){                              // easum means from 90 partials
    const float* ps = wv ? p.psd : p.psc;
    float v = ps[lane] + (lane + 64 < GBK ? ps[lane + 64] : 0.0f);
    #pragma unroll
    for (int off = 32; off; off >>= 1) v += __shfl_down(v, off, 64);
    if (lane == 0) p.easum[wv] = v / (wv ? (float)EDD : (float)ECC);
  }
  { // wedot[w] = <We[h], a_edge[h]>, w = br*8+h (16 waves)
    int hh = wv & 7;
    const float* We = (wv >= 8) ? p.we_d : p.we_c;
    const float* Ae = (wv >= 8) ? p.ae_d : p.ae_c;
    float v = We[hh * DIM + lane] * Ae[hh * DIM + lane]
            + We[hh * DIM + 64 + lane] * Ae[hh * DIM + 64 + lane];
    #pragma unroll
    for (int off = 32; off; off >>= 1) v += __shfl_down(v, off, 64);
    if (lane == 0) p.wedot[wv] = v;
  }
}

// ---- multi-block CSR fill: global cursor atomics + scattered stores ----
__global__ __launch_bounds__(256) void k_fill(P p){
  int e = blockIdx.x * 256 + threadIdx.x;
  if (e >= ET) return;
  int s, d;
  if (e < ECC){ s = p.csrc[e]; d = p.cdst[e]; }
  else { int el = e - ECC; s = NCIR + p.dsrc[el]; d = NCIR + p.ddst[el]; }
  int pos = atomicAdd(&p.cursor[d], 1);
  p.fill_s[pos] = s;
  p.fill_w[pos] = p.ew[e];
}

// ---- GCN1 dense: h[u] = x[u] @ W1 ----
__global__ void k_gemm128(P p){
  __shared__ float a_sh[DIM];
  int u = blockIdx.x, t = threadIdx.x;      // 128 threads
  int br = u >= NCIR;
  a_sh[t] = br ? p.x_d[(u - NCIR) * DIM + t] : p.x_c[u * DIM + t];
  __syncthreads();
  const float* W = br ? p.g1w_d : p.g1w_c;
  float acc = 0.0f;
  #pragma unroll 8
  for (int c = 0; c < DIM; ++c) acc += a_sh[c] * W[c * DIM + t];
  p.h[u * DIM + t] = acc;
}

// ---- fuse1: GCN1 agg -> f1 -> relu -> GAT proj (hg) -> attention dots ----
__global__ __launch_bounds__(256) void k_fuse1(P p){
  __shared__ float a_sh[4][DIM];
  int b = blockIdx.x, t = threadIdx.x;      // 256 threads, 4 nodes
  int base, count, br;
  if (b < F1C){ base = b * 4; count = min(4, NCIR - base); br = 0; }
  else { base = NCIR + (b - F1C) * 4; count = 4; br = 1; }
  const float* B1 = br ? p.g1b_d : p.g1b_c;
  int n2 = t >> 7, k = t & 127;
  for (int r = 0; r < 2; ++r){
    int nn = n2 + r * 2;
    float v = 0.0f;
    if (nn < count){
      int u = base + nn;
      float dv = p.dinv[u];
      float acc = B1[k] + p.h[u * DIM + k] * dv * dv;
      int beg = p.rowptr[u], end = p.rowptr[u + 1];
      for (int j = beg; j < end; ++j){
        int s = p.fill_s[j];
        acc += p.h[s * DIM + k] * (p.dinv[s] * p.fill_w[j] * dv);
      }
      p.f1[u * DIM + k] = acc;
      v = fmaxf(acc, 0.0f);
    }
    a_sh[nn][k] = v;
  }
  __syncthreads();
  const float4* Wv = (const float4*)(br ? p.aw_d : p.aw_c);  // row = 256 float4
  float4 acc4[4];
  #pragma unroll
  for (int n = 0; n < 4; ++n) acc4[n] = make_float4(0.f, 0.f, 0.f, 0.f);
  #pragma unroll 2
  for (int c = 0; c < DIM; ++c){
    float4 w = Wv[c * 256 + t];
    #pragma unroll
    for (int n = 0; n < 4; ++n){
      float a = a_sh[n][c];
      acc4[n].x += a * w.x; acc4[n].y += a * w.y;
      acc4[n].z += a * w.z; acc4[n].w += a * w.w;
    }
  }
  for (int n = 0; n < count; ++n)
    *(float4*)(p.hg + (size_t)(base + n) * 1024 + t * 4) = acc4[n];
  // dots straight from accumulator registers: thread t holds cols t*4..t*4+3
  const float* As = br ? p.as_d : p.as_c;
  const float* Ad = br ? p.ad_d : p.ad_c;
  int hh = t >> 5, kb = (t & 31) * 4;       // head, col-within-head
  #pragma unroll
  for (int n = 0; n < 4; ++n){
    float sdot = 0.0f, ddot = 0.0f;
    const float* A4 = (const float*)&acc4[n];
    #pragma unroll
    for (int q = 0; q < 4; ++q){
      sdot += A4[q] * As[hh * DIM + kb + q];
      ddot += A4[q] * Ad[hh * DIM + kb + q];
    }
    #pragma unroll
    for (int off = 16; off; off >>= 1){     // reduce 32-lane head group
      sdot += __shfl_down(sdot, off, 64);
      ddot += __shfl_down(ddot, off, 64);
    }
    if ((t & 31) == 0 && n < count){
      p.hs[(base + n) * NH + hh] = sdot;
      p.hd[(base + n) * NH + hh] = ddot;
    }
  }
}

// ---- att: softmax-agg per dst (alphas via LDS, chunked) + fused GCN2 dense.
// (segment-max shift skipped: logits O(1), exp cannot overflow; softmax is
//  shift-invariant so the result is identical.) ----
__global__ __launch_bounds__(128) void k_att(P p){
  __shared__ float den_sh[NH], hd_sh[NH], inv_sh[NH], wself_sh[NH];
  __shared__ float alpha_sh[CH * NH];
  __shared__ int   s_sh[CH];
  __shared__ float a_sh[DIM];
  int d = blockIdx.x, t = threadIdx.x;      // 128 threads
  int br = d >= NCIR;
  const float* wd = p.wedot + br * NH;
  if (t < NH){ den_sh[t] = 0.0f; hd_sh[t] = p.hd[d * NH + t]; }
  __syncthreads();
  int beg = p.rowptr[d], end = p.rowptr[d + 1];
  int deg = end - beg;
  float slw = p.easum[br];                  // self-loop edge weight = mean(ew)
  for (int idx = t; idx < deg * NH; idx += 128){
    int j = beg + (idx >> 3), hh = idx & 7;
    int s = p.fill_s[j];
    float a = p.hs[s * NH + hh] + hd_sh[hh] + p.fill_w[j] * wd[hh];
    a = a > 0.0f ? a : 0.2f * a;
    atomicAdd(&den_sh[hh], expf(a));
  }
  __syncthreads();
  if (t < NH){
    float a = p.hs[d * NH + t] + hd_sh[t] + slw * wd[t];
    a = a > 0.0f ? a : 0.2f * a;
    float ex = expf(a);
    float inv = 1.0f / (den_sh[t] + ex + 1e-16f) * 0.125f;  // /(den+eps)/H
    inv_sh[t] = inv;
    wself_sh[t] = ex * inv;
  }
  __syncthreads();
  float acc = (br ? p.ab_d : p.ab_c)[t];
  {
    const float* r = p.hg + (size_t)d * 1024;
    #pragma unroll
    for (int hh = 0; hh < NH; ++hh) acc += wself_sh[hh] * r[hh * DIM + t];
  }
  for (int j0 = beg; j0 < end; j0 += CH){
    int m = min(CH, end - j0);
    for (int idx = t; idx < m * NH; idx += 128){
      int jj = idx >> 3, hh = idx & 7;
      int j = j0 + jj;
      int s = p.fill_s[j];
      float a = p.hs[s * NH + hh] + hd_sh[hh] + p.fill_w[j] * wd[hh];
      a = a > 0.0f ? a : 0.2f * a;
      alpha_sh[idx] = expf(a) * inv_sh[hh];
    }
    if (t < m) s_sh[t] = p.fill_s[j0 + t];
    __syncthreads();
    for (int jj = 0; jj < m; ++jj){
      const float* r = p.hg + (size_t)s_sh[jj] * 1024;
      #pragma unroll
      for (int hh = 0; hh < NH; ++hh) acc += alpha_sh[jj * NH + hh] * r[hh * DIM + t];
    }
    __syncthreads();
  }
  // fused GCN2 dense: h2[d] = relu(att[d]) @ W2 (att never leaves the block)
  a_sh[t] = fmaxf(acc, 0.0f);
  __syncthreads();
  const float* W = br ? p.g2w_d : p.g2w_c;
  float h2 = 0.0f;
  #pragma unroll 8
  for (int c = 0; c < DIM; ++c) h2 += a_sh[c] * W[c * DIM + t];
  p.h[d * DIM + t] = h2;
}

// ---- fuse2: GCN2 agg -> f2 -> CNN head (f2 never leaves the block) ----
__global__ __launch_bounds__(256) void k_fuse2(P p){
  __shared__ float s12[4][2 * DIM];
  int b = blockIdx.x, o = threadIdx.x;      // 256 threads, 4 nodes
  int gbase, count, br; float* out;
  if (b < F1C){ gbase = b * 4; count = min(4, NCIR - gbase); br = 0;
                out = p.out_cir + (size_t)gbase * CO; }
  else { int lb = (b - F1C) * 4; gbase = NCIR + lb; count = 4; br = 1;
         out = p.out_dis + (size_t)lb * CO; }
  const float* B2 = br ? p.g2b_d : p.g2b_c;
  int n2 = o >> 7, k = o & 127;
  for (int r = 0; r < 2; ++r){
    int nn = n2 + r * 2;
    float v1 = 0.0f, v2 = 0.0f;
    if (nn < count){
      int u = gbase + nn;
      float dv = p.dinv[u];
      float acc = B2[k] + p.h[u * DIM + k] * dv * dv;
      int beg = p.rowptr[u], end = p.rowptr[u + 1];
      for (int j = beg; j < end; ++j){
        int s = p.fill_s[j];
        acc += p.h[s * DIM + k] * (p.dinv[s] * p.fill_w[j] * dv);
      }
      v2 = fmaxf(acc, 0.0f);
      v1 = fmaxf(p.f1[u * DIM + k], 0.0f);
    }
    s12[nn][k] = v1;
    s12[nn][DIM + k] = v2;
  }
  __syncthreads();
  const float* W = (br ? p.cw_d : p.cw_c) + o * 2 * DIM;
  float bv = (br ? p.cb_d : p.cb_c)[o];
  float a0 = bv, a1 = bv, a2 = bv, a3 = bv;
  #pragma unroll 4
  for (int q = 0; q < 2 * DIM; ++q){
    float wv = W[q];
    a0 += s12[0][q] * wv; a1 += s12[1][q] * wv;
    a2 += s12[2][q] * wv; a3 += s12[3][q] * wv;
  }
  if (0 < count) out[0 * CO + o] = a0;
  if (1 < count) out[1 * CO + o] = a1;
  if (2 < count) out[2 * CO + o] = a2;
  if (3 < count) out[3 * CO + o] = a3;
}

// ---- score[i,j] = <cir[i,:], dis[j,:]> ----
__global__ void k_final(P p){
  __shared__ float ci[CO];
  int i = blockIdx.x, j = threadIdx.x;      // 128 threads, 88 active
  ci[j]       = p.out_cir[i * CO + j];
  ci[DIM + j] = p.out_cir[i * CO + DIM + j];
  __syncthreads();
  if (j < NDIS){
    const float* dr = p.out_dis + j * CO;
    float acc = 0.0f;
    #pragma unroll 8
    for (int q = 0; q < CO; ++q) acc += ci[q] * dr[q];
    p.out_score[i * NDIS + j] = acc;
  }
}

extern "C" void kernel_launch(void* const* d_in, const int* in_sizes, int n_in,
                              void* d_out, int out_size, void* d_ws, size_t ws_size,
                              hipStream_t stream){
  P p;
  typedef const float* F;
  p.x_c   = (F)d_in[0];  p.x_d   = (F)d_in[1];
  p.mat_c = (F)d_in[2];  p.mat_d = (F)d_in[3];
  p.g1w_c = (F)d_in[4];  p.g1b_c = (F)d_in[5];
  p.aw_c  = (F)d_in[6];  p.as_c  = (F)d_in[7];  p.ad_c = (F)d_in[8];
  p.ae_c  = (F)d_in[9];  p.we_c  = (F)d_in[10]; p.ab_c = (F)d_in[11];
  p.g2w_c = (F)d_in[12]; p.g2b_c = (F)d_in[13];
  p.g1w_d = (F)d_in[14]; p.g1b_d = (F)d_in[15];
  p.aw_d  = (F)d_in[16]; p.as_d  = (F)d_in[17]; p.ad_d = (F)d_in[18];
  p.ae_d  = (F)d_in[19]; p.we_d  = (F)d_in[20]; p.ab_d = (F)d_in[21];
  p.g2w_d = (F)d_in[22]; p.g2b_d = (F)d_in[23];
  p.cw_c  = (F)d_in[24]; p.cb_c  = (F)d_in[25];
  p.cw_d  = (F)d_in[26]; p.cb_d  = (F)d_in[27];
  const int* cc_edges = (const int*)d_in[28];
  const int* dd_edges = (const int*)d_in[29];
  p.csrc = cc_edges;  p.cdst = cc_edges + ECC;
  p.dsrc = dd_edges;  p.ddst = dd_edges + EDD;

  float* out = (float*)d_out;
  p.out_score = out;                        // [585, 88]
  p.out_cir   = out + NCIR * NDIS;          // [585, 256]
  p.out_dis   = p.out_cir + NCIR * CO;      // [88, 256]

  float* w = (float*)d_ws;                  // ~3.8 MB of 256 MB; 16B-aligned blocks
  auto alloc = [&](size_t n){ float* q = w; w += n; return q; };
  p.ew     = alloc(ET);                     // 23000 (%4==0)
  p.wdeg   = alloc(676);                    // zeroed by memset (cnt adjacent)
  p.cnt    = (int*)alloc(676);
  p.dinv   = alloc(676);
  p.easum  = alloc(4);
  p.wedot  = alloc(16);
  p.psc    = alloc(92);
  p.psd    = alloc(92);
  p.hs     = alloc((size_t)NT * NH);        // 5384 (%4==0)
  p.hd     = alloc((size_t)NT * NH);
  p.h      = alloc((size_t)NT * DIM);
  p.f1     = alloc((size_t)NT * DIM);
  p.hg     = alloc((size_t)NT * 1024);
  p.fill_w = alloc(ET);
  p.cursor = (int*)alloc(676);
  p.rowptr = (int*)alloc(680);
  p.fill_s = (int*)alloc(ET);

  hipMemsetAsync(p.wdeg, 0, 2 * 676 * sizeof(float), stream);  // wdeg + cnt
  k_gather <<<GBK,         256,  0, stream>>>(p);
  k_scan   <<<1,           1024, 0, stream>>>(p);
  k_fill   <<<GBK,         256,  0, stream>>>(p);
  k_gemm128<<<NT,          DIM,  0, stream>>>(p);
  k_fuse1  <<<F1C + F1D,   256,  0, stream>>>(p);
  k_att    <<<NT,          DIM,  0, stream>>>(p);
  k_fuse2  <<<F1C + F1D,   256,  0, stream>>>(p);
  k_final  <<<NCIR,        DIM,  0, stream>>>(p);
}

// Round 12
// 216.494 us; speedup vs baseline: 1.4115x; 1.1643x over previous
//
#include <hip/hip_runtime.h>

constexpr int NCIR = 585;
constexpr int NDIS = 88;
constexpr int NT   = NCIR + NDIS;   // 673 nodes (c: [0,585), d: [585,673))
constexpr int DIM  = 128;
constexpr int NH   = 8;
constexpr int ECC  = 20000;
constexpr int EDD  = 3000;
constexpr int ET   = ECC + EDD;     // 23000 edges
constexpr int CO   = 256;
constexpr int F1C  = (NCIR + 3) / 4;   // 147 c node-groups (4 nodes)
constexpr int F1D  = (NDIS + 3) / 4;   // 22 d node-groups
constexpr int NG   = F1C + F1D;        // 169 groups -> proj grid = NG*4
constexpr int CH   = 64;               // att chunk (edges per LDS sweep)
constexpr int GBK  = (ET + 255) / 256; // 90 gather blocks
constexpr int GEMB = (NT + 1) / 2;     // 337 gemm128 blocks (2 nodes each)

struct P {
  const float *x_c, *x_d, *mat_c, *mat_d;
  const float *g1w_c, *g1b_c, *aw_c, *as_c, *ad_c, *ae_c, *we_c, *ab_c, *g2w_c, *g2b_c;
  const float *g1w_d, *g1b_d, *aw_d, *as_d, *ad_d, *ae_d, *we_d, *ab_d, *g2w_d, *g2b_d;
  const float *cw_c, *cb_c, *cw_d, *cb_d;
  const int *csrc, *cdst, *dsrc, *ddst;
  float *ew, *dinv, *easum, *wedot, *hs, *hd, *h, *f1, *hg, *fill_w, *psc, *psd, *wdeg;
  int *cnt, *cursor, *rowptr, *fill_s;
  float *out_score, *out_cir, *out_dis;
};

// ---- merged: blocks [0,90) edge gather (global atomics); blocks [90,427)
//      GCN1 dense h = x @ W1, 2 nodes/block. Data-independent halves. ----
__global__ __launch_bounds__(256) void k_gg(P p){
  __shared__ float r0[256], r1[256];
  int b = blockIdx.x, t = threadIdx.x;
  if (b < GBK){
    int e = b * 256 + t;
    float wc = 0.0f, wdv = 0.0f;
    if (e < ET){
      float w; int d;
      if (e < ECC){
        int s = p.csrc[e]; d = p.cdst[e];
        w = p.mat_c[s * NCIR + d]; wc = w;
      } else {
        int el = e - ECC;
        int s = p.dsrc[el]; d = NCIR + p.ddst[el];
        w = p.mat_d[s * NDIS + (d - NCIR)]; wdv = w;
      }
      p.ew[e] = w;
      atomicAdd(&p.wdeg[d], w);
      atomicAdd(&p.cnt[d], 1);
    }
    r0[t] = wc; r1[t] = wdv;
    __syncthreads();
    for (int st = 128; st; st >>= 1){
      if (t < st){ r0[t] += r0[t + st]; r1[t] += r1[t + st]; }
      __syncthreads();
    }
    if (t == 0){ p.psc[b] = r0[0]; p.psd[b] = r1[0]; }
  } else {
    float* a_sh = r0;                       // reuse LDS: a_sh[2][128]
    int ub = (b - GBK) * 2;
    int n = t >> 7, k = t & 127;
    int u = ub + n;
    bool ok = u < NT;
    if (ok){
      int br = u >= NCIR;
      a_sh[n * DIM + k] = br ? p.x_d[(u - NCIR) * DIM + k] : p.x_c[u * DIM + k];
    }
    __syncthreads();
    if (ok){
      const float* W = (u >= NCIR) ? p.g1w_d : p.g1w_c;
      float acc = 0.0f;
      #pragma unroll 8
      for (int c = 0; c < DIM; ++c) acc += a_sh[n * DIM + c] * W[c * DIM + k];
      p.h[u * DIM + k] = acc;
    }
  }
}

// ---- single-block serial work: scan -> rowptr/cursor, dinv, easum, wedot ----
__global__ __launch_bounds__(1024) void k_scan(P p){
  __shared__ int sd[1024];
  int t = threadIdx.x;
  int v0 = (t < NT) ? p.cnt[t] : 0;
  sd[t] = v0;
  __syncthreads();
  for (int off = 1; off < 1024; off <<= 1){
    int v = (t >= off) ? sd[t - off] : 0;
    __syncthreads();
    sd[t] += v;
    __syncthreads();
  }
  if (t < NT){
    p.rowptr[t + 1] = sd[t];
    p.cursor[t]     = sd[t] - v0;           // exclusive scan
    p.dinv[t] = rsqrtf(1.0f + p.wdeg[t]);   // self-loop 1 + weighted in-deg
  }
  if (t == 0) p.rowptr[0] = 0;
  int wv = t >> 6, lane = t & 63;
  if (wv < 2){                              // easum means from 90 partials
    const float* ps = wv ? p.psd : p.psc;
    float v = ps[lane] + (lane + 64 < GBK ? ps[lane + 64] : 0.0f);
    #pragma unroll
    for (int off = 32; off; off >>= 1) v += __shfl_down(v, off, 64);
    if (lane == 0) p.easum[wv] = v / (wv ? (float)EDD : (float)ECC);
  }
  { // wedot[w] = <We[h], a_edge[h]>, w = br*8+h (16 waves)
    int hh = wv & 7;
    const float* We = (wv >= 8) ? p.we_d : p.we_c;
    const float* Ae = (wv >= 8) ? p.ae_d : p.ae_c;
    float v = We[hh * DIM + lane] * Ae[hh * DIM + lane]
            + We[hh * DIM + 64 + lane] * Ae[hh * DIM + 64 + lane];
    #pragma unroll
    for (int off = 32; off; off >>= 1) v += __shfl_down(v, off, 64);
    if (lane == 0) p.wedot[wv] = v;
  }
}

// ---- multi-block CSR fill ----
__global__ __launch_bounds__(256) void k_fill(P p){
  int e = blockIdx.x * 256 + threadIdx.x;
  if (e >= ET) return;
  int s, d;
  if (e < ECC){ s = p.csrc[e]; d = p.cdst[e]; }
  else { int el = e - ECC; s = NCIR + p.dsrc[el]; d = NCIR + p.ddst[el]; }
  int pos = atomicAdd(&p.cursor[d], 1);
  p.fill_s[pos] = s;
  p.fill_w[pos] = p.ew[e];
}

// ---- GCN1 aggregation: per-dst CSR gather -> f1 ----
__global__ __launch_bounds__(128) void k_agg1(P p){
  int d = blockIdx.x, k = threadIdx.x;      // 128 threads
  int br = d >= NCIR;
  const float* B1 = br ? p.g1b_d : p.g1b_c;
  float dv = p.dinv[d];
  float acc = B1[k] + p.h[d * DIM + k] * dv * dv;
  int beg = p.rowptr[d], end = p.rowptr[d + 1];
  for (int j = beg; j < end; ++j){
    int s = p.fill_s[j];
    acc += p.h[s * DIM + k] * (p.dinv[s] * p.fill_w[j] * dv);
  }
  p.f1[d * DIM + k] = acc;
}

// ---- GAT projection, col-tiled: block = 4 nodes x 256 cols; 676 blocks.
//      Also computes the two heads' attention dots in-block. ----
__global__ __launch_bounds__(256) void k_proj(P p){
  __shared__ float a_sh[4][DIM];
  __shared__ float wred[4][8];
  int b = blockIdx.x, t = threadIdx.x;
  int ng = b >> 2, ct = b & 3;
  int base, count, br;
  if (ng < F1C){ base = ng * 4; count = min(4, NCIR - base); br = 0; }
  else { base = NCIR + (ng - F1C) * 4; count = 4; br = 1; }
  // stage relu(f1) for the 4 nodes
  for (int i = 0; i < 2; ++i){
    int idx = t + i * 256, n = idx >> 7, c = idx & 127;
    a_sh[n][c] = (n < count) ? fmaxf(p.f1[(base + n) * DIM + c], 0.0f) : 0.0f;
  }
  __syncthreads();
  const float* W = (br ? p.aw_d : p.aw_c) + ct * 256 + t;   // col = ct*256+t
  float acc[4] = {0.f, 0.f, 0.f, 0.f};
  #pragma unroll 4
  for (int c = 0; c < DIM; ++c){
    float w = W[c * 1024];
    acc[0] += a_sh[0][c] * w; acc[1] += a_sh[1][c] * w;
    acc[2] += a_sh[2][c] * w; acc[3] += a_sh[3][c] * w;
  }
  int col = ct * 256 + t;
  for (int n = 0; n < count; ++n)
    p.hg[(size_t)(base + n) * 1024 + col] = acc[n];
  // dots for the 2 heads this block covers (head = col>>7)
  const float* As = br ? p.as_d : p.as_c;   // [8][128] contiguous -> As[col]
  const float* Ad = br ? p.ad_d : p.ad_c;
  float av = As[col], dw = Ad[col];
  int w = t >> 6;                           // wave 0..3 (waves 0,1 = head ct*2)
  #pragma unroll
  for (int n = 0; n < 4; ++n){
    float sdot = acc[n] * av, ddot = acc[n] * dw;
    #pragma unroll
    for (int off = 32; off; off >>= 1){
      sdot += __shfl_down(sdot, off, 64);
      ddot += __shfl_down(ddot, off, 64);
    }
    if ((t & 63) == 0){ wred[w][n * 2] = sdot; wred[w][n * 2 + 1] = ddot; }
  }
  __syncthreads();
  if (t < 16){
    int g = t >> 3, v = t & 7, n = v >> 1, isd = v & 1;
    if (n < count){
      float sum = wred[g * 2][v] + wred[g * 2 + 1][v];
      float* dst = isd ? p.hd : p.hs;
      dst[(base + n) * NH + ct * 2 + g] = sum;
    }
  }
}

// ---- att: per-dst softmax-agg, 256 threads. ALL threads iterate the SAME
//      chunk loop (uniform barriers — R11's group-split loop had divergent
//      __syncthreads counts when deg < CH: race, absmax 0.157). Within a
//      chunk, group g consumes alternate edges. + fused K-split GCN2 dense.
//      (segment-max shift skipped: logits O(1), exp cannot overflow;
//       softmax is shift-invariant -> identical result.) ----
__global__ __launch_bounds__(256) void k_att(P p){
  __shared__ float den_sh[NH], hd_sh[NH], inv_sh[NH], wself_sh[NH];
  __shared__ float alpha_sh[CH * NH];
  __shared__ int   s_sh[CH];
  __shared__ float a2[2][DIM];
  __shared__ float attv[DIM];
  __shared__ float part[2][DIM];
  int d = blockIdx.x, t = threadIdx.x;
  int g = t >> 7, k = t & 127;
  int br = d >= NCIR;
  const float* wd = p.wedot + br * NH;
  if (t < NH){ den_sh[t] = 0.0f; hd_sh[t] = p.hd[d * NH + t]; }
  __syncthreads();
  int beg = p.rowptr[d], end = p.rowptr[d + 1];
  int deg = end - beg;
  float slw = p.easum[br];                  // self-loop edge weight = mean(ew)
  for (int idx = t; idx < deg * NH; idx += 256){
    int j = beg + (idx >> 3), hh = idx & 7;
    int s = p.fill_s[j];
    float a = p.hs[s * NH + hh] + hd_sh[hh] + p.fill_w[j] * wd[hh];
    a = a > 0.0f ? a : 0.2f * a;
    atomicAdd(&den_sh[hh], expf(a));
  }
  __syncthreads();
  if (t < NH){
    float a = p.hs[d * NH + t] + hd_sh[t] + slw * wd[t];
    a = a > 0.0f ? a : 0.2f * a;
    float ex = expf(a);
    float inv = 1.0f / (den_sh[t] + ex + 1e-16f) * 0.125f;  // /(den+eps)/H
    inv_sh[t] = inv;
    wself_sh[t] = ex * inv;
  }
  __syncthreads();
  // group 0 seeds bias + self-loop; group 1 accumulates pure edge share
  float acc = 0.0f;
  if (g == 0){
    acc = (br ? p.ab_d : p.ab_c)[k];
    const float* r = p.hg + (size_t)d * 1024;
    #pragma unroll
    for (int hh = 0; hh < NH; ++hh) acc += wself_sh[hh] * r[hh * DIM + k];
  }
  for (int j0 = beg; j0 < end; j0 += CH){   // uniform loop: same trip count
    int m = min(CH, end - j0);              // for every thread in the block
    for (int idx = t; idx < m * NH; idx += 256){
      int jj = idx >> 3, hh = idx & 7;
      int j = j0 + jj;
      int s = p.fill_s[j];
      float a = p.hs[s * NH + hh] + hd_sh[hh] + p.fill_w[j] * wd[hh];
      a = a > 0.0f ? a : 0.2f * a;
      alpha_sh[idx] = expf(a) * inv_sh[hh];
    }
    if (t < m) s_sh[t] = p.fill_s[j0 + t];
    __syncthreads();
    for (int jj = g; jj < m; jj += 2){      // group g: alternate edges, no barrier
      const float* r = p.hg + (size_t)s_sh[jj] * 1024;
      #pragma unroll
      for (int hh = 0; hh < NH; ++hh) acc += alpha_sh[jj * NH + hh] * r[hh * DIM + k];
    }
    __syncthreads();
  }
  a2[g][k] = acc;
  __syncthreads();
  if (g == 0) attv[k] = fmaxf(a2[0][k] + a2[1][k], 0.0f);   // att[d][k]
  __syncthreads();
  // K-split GCN2 dense: group g covers c in [g*64, g*64+64)
  const float* W = br ? p.g2w_d : p.g2w_c;
  float h2 = 0.0f;
  #pragma unroll 8
  for (int c = g * 64; c < g * 64 + 64; ++c) h2 += attv[c] * W[c * DIM + k];
  part[g][k] = h2;
  __syncthreads();
  if (g == 0) p.h[d * DIM + k] = part[0][k] + part[1][k];
}

// ---- fuse2: GCN2 agg -> f2 -> CNN head (f2 never leaves the block) ----
__global__ __launch_bounds__(256) void k_fuse2(P p){
  __shared__ float s12[4][2 * DIM];
  int b = blockIdx.x, o = threadIdx.x;      // 256 threads, 4 nodes
  int gbase, count, br; float* out;
  if (b < F1C){ gbase = b * 4; count = min(4, NCIR - gbase); br = 0;
                out = p.out_cir + (size_t)gbase * CO; }
  else { int lb = (b - F1C) * 4; gbase = NCIR + lb; count = 4; br = 1;
         out = p.out_dis + (size_t)lb * CO; }
  const float* B2 = br ? p.g2b_d : p.g2b_c;
  int n2 = o >> 7, k = o & 127;
  for (int r = 0; r < 2; ++r){
    int nn = n2 + r * 2;
    float v1 = 0.0f, v2 = 0.0f;
    if (nn < count){
      int u = gbase + nn;
      float dv = p.dinv[u];
      float acc = B2[k] + p.h[u * DIM + k] * dv * dv;
      int beg = p.rowptr[u], end = p.rowptr[u + 1];
      for (int j = beg; j < end; ++j){
        int s = p.fill_s[j];
        acc += p.h[s * DIM + k] * (p.dinv[s] * p.fill_w[j] * dv);
      }
      v2 = fmaxf(acc, 0.0f);
      v1 = fmaxf(p.f1[u * DIM + k], 0.0f);
    }
    s12[nn][k] = v1;
    s12[nn][DIM + k] = v2;
  }
  __syncthreads();
  const float* W = (br ? p.cw_d : p.cw_c) + o * 2 * DIM;
  float bv = (br ? p.cb_d : p.cb_c)[o];
  float a0 = bv, a1 = bv, a2 = bv, a3 = bv;
  #pragma unroll 4
  for (int q = 0; q < 2 * DIM; ++q){
    float wv = W[q];
    a0 += s12[0][q] * wv; a1 += s12[1][q] * wv;
    a2 += s12[2][q] * wv; a3 += s12[3][q] * wv;
  }
  if (0 < count) out[0 * CO + o] = a0;
  if (1 < count) out[1 * CO + o] = a1;
  if (2 < count) out[2 * CO + o] = a2;
  if (3 < count) out[3 * CO + o] = a3;
}

// ---- score[i,j] = <cir[i,:], dis[j,:]> ----
__global__ void k_final(P p){
  __shared__ float ci[CO];
  int i = blockIdx.x, j = threadIdx.x;      // 128 threads, 88 active
  ci[j]       = p.out_cir[i * CO + j];
  ci[DIM + j] = p.out_cir[i * CO + DIM + j];
  __syncthreads();
  if (j < NDIS){
    const float* dr = p.out_dis + j * CO;
    float acc = 0.0f;
    #pragma unroll 8
    for (int q = 0; q < CO; ++q) acc += ci[q] * dr[q];
    p.out_score[i * NDIS + j] = acc;
  }
}

extern "C" void kernel_launch(void* const* d_in, const int* in_sizes, int n_in,
                              void* d_out, int out_size, void* d_ws, size_t ws_size,
                              hipStream_t stream){
  P p;
  typedef const float* F;
  p.x_c   = (F)d_in[0];  p.x_d   = (F)d_in[1];
  p.mat_c = (F)d_in[2];  p.mat_d = (F)d_in[3];
  p.g1w_c = (F)d_in[4];  p.g1b_c = (F)d_in[5];
  p.aw_c  = (F)d_in[6];  p.as_c  = (F)d_in[7];  p.ad_c = (F)d_in[8];
  p.ae_c  = (F)d_in[9];  p.we_c  = (F)d_in[10]; p.ab_c = (F)d_in[11];
  p.g2w_c = (F)d_in[12]; p.g2b_c = (F)d_in[13];
  p.g1w_d = (F)d_in[14]; p.g1b_d = (F)d_in[15];
  p.aw_d  = (F)d_in[16]; p.as_d  = (F)d_in[17]; p.ad_d = (F)d_in[18];
  p.ae_d  = (F)d_in[19]; p.we_d  = (F)d_in[20]; p.ab_d = (F)d_in[21];
  p.g2w_d = (F)d_in[22]; p.g2b_d = (F)d_in[23];
  p.cw_c  = (F)d_in[24]; p.cb_c  = (F)d_in[25];
  p.cw_d  = (F)d_in[26]; p.cb_d  = (F)d_in[27];
  const int* cc_edges = (const int*)d_in[28];
  const int* dd_edges = (const int*)d_in[29];
  p.csrc = cc_edges;  p.cdst = cc_edges + ECC;
  p.dsrc = dd_edges;  p.ddst = dd_edges + EDD;

  float* out = (float*)d_out;
  p.out_score = out;                        // [585, 88]
  p.out_cir   = out + NCIR * NDIS;          // [585, 256]
  p.out_dis   = p.out_cir + NCIR * CO;      // [88, 256]

  float* w = (float*)d_ws;                  // ~3.8 MB of 256 MB
  auto alloc = [&](size_t n){ float* q = w; w += n; return q; };
  p.ew     = alloc(ET);
  p.wdeg   = alloc(676);                    // zeroed by memset (cnt adjacent)
  p.cnt    = (int*)alloc(676);
  p.dinv   = alloc(676);
  p.easum  = alloc(4);
  p.wedot  = alloc(16);
  p.psc    = alloc(92);
  p.psd    = alloc(92);
  p.hs     = alloc((size_t)NT * NH);
  p.hd     = alloc((size_t)NT * NH);
  p.h      = alloc((size_t)NT * DIM);
  p.f1     = alloc((size_t)NT * DIM);
  p.hg     = alloc((size_t)NT * 1024);
  p.fill_w = alloc(ET);
  p.cursor = (int*)alloc(676);
  p.rowptr = (int*)alloc(680);
  p.fill_s = (int*)alloc(ET);

  hipMemsetAsync(p.wdeg, 0, 2 * 676 * sizeof(float), stream);  // wdeg + cnt
  k_gg    <<<GBK + GEMB, 256,  0, stream>>>(p);
  k_scan  <<<1,          1024, 0, stream>>>(p);
  k_fill  <<<GBK,        256,  0, stream>>>(p);
  k_agg1  <<<NT,         DIM,  0, stream>>>(p);
  k_proj  <<<NG * 4,     256,  0, stream>>>(p);
  k_att   <<<NT,         256,  0, stream>>>(p);
  k_fuse2 <<<F1C + F1D,  256,  0, stream>>>(p);
  k_final <<<NCIR,       DIM,  0, stream>>>(p);
}